// Round 2
// baseline (960.875 us; speedup 1.0000x reference)
//
#include <hip/hip_runtime.h>
#include <stdint.h>

#define B_  4
#define S_  2048
#define H_  16
#define DH_ 64
#define DM_ 1024

typedef __attribute__((ext_vector_type(8))) short bf16x8;  // 8 bf16 = 4 VGPR
typedef __attribute__((ext_vector_type(4))) float f32x4;

__device__ __forceinline__ ushort f2bf(float x){
  uint32_t u = __float_as_uint(x);
  u += 0x7FFFu + ((u >> 16) & 1u);   // RNE
  return (ushort)(u >> 16);
}
__device__ __forceinline__ uint32_t pack2(float a, float b){
  return (uint32_t)f2bf(a) | ((uint32_t)f2bf(b) << 16);
}
// truncating bf16 pack: low16 = hi(a), high16 = hi(b). 1 v_perm_b32.
__device__ __forceinline__ uint32_t packtr(float a, float b){
  return __builtin_amdgcn_perm(__float_as_uint(b), __float_as_uint(a), 0x07060302u);
}
__device__ __forceinline__ f32x4 zero4(){ f32x4 z; z.x=0.f;z.y=0.f;z.z=0.f;z.w=0.f; return z; }

__device__ __forceinline__ void async16(void* lds, const void* g){
  __builtin_amdgcn_global_load_lds(
      (const __attribute__((address_space(1))) unsigned int*)g,
      (__attribute__((address_space(3))) unsigned int*)lds, 16, 0, 0);
}

// ---------------------------------------------------------------------------
// X fp32 -> bf16 (RNE), all three input tensors in one launch (blockIdx.y).
// ---------------------------------------------------------------------------
__global__ __launch_bounds__(256) void conv3(const float* __restrict__ a,
                                             const float* __restrict__ b,
                                             const float* __restrict__ c,
                                             ushort* __restrict__ oa,
                                             ushort* __restrict__ ob,
                                             ushort* __restrict__ oc){
  const float* src = (blockIdx.y==0) ? a : (blockIdx.y==1) ? b : c;
  ushort* dst      = (blockIdx.y==0) ? oa : (blockIdx.y==1) ? ob : oc;
  size_t i = ((size_t)blockIdx.x*256 + threadIdx.x)*8;   // grid covers exactly 8M
  float4 x0 = *(const float4*)&src[i];
  float4 x1 = *(const float4*)&src[i+4];
  uint4 p;
  p.x = pack2(x0.x,x0.y); p.y = pack2(x0.z,x0.w);
  p.z = pack2(x1.x,x1.y); p.w = pack2(x1.z,x1.w);
  *(uint4*)&dst[i] = p;
}

// ---------------------------------------------------------------------------
// W [K][N] fp32 -> Wt [N][K] bf16 (transpose + convert), 3 weights batched.
// ---------------------------------------------------------------------------
__global__ __launch_bounds__(256) void wtrans3(const float* __restrict__ Wq,
                                               const float* __restrict__ Wk,
                                               const float* __restrict__ Wv,
                                               ushort* __restrict__ Tq,
                                               ushort* __restrict__ Tk,
                                               ushort* __restrict__ Tv){
  const float* W = (blockIdx.z==0) ? Wq : (blockIdx.z==1) ? Wk : Wv;
  ushort* Wt     = (blockIdx.z==0) ? Tq : (blockIdx.z==1) ? Tk : Tv;
  __shared__ __align__(16) float t[32][33];
  int n0 = blockIdx.x * 32, k0 = blockIdx.y * 32;
  int col = threadIdx.x & 31, rg = threadIdx.x >> 5;
  #pragma unroll
  for (int i = 0; i < 4; i++){
    int r = rg + i*8;
    t[r][col] = W[(size_t)(k0 + r) * DM_ + n0 + col];
  }
  __syncthreads();
  #pragma unroll
  for (int i = 0; i < 4; i++){
    int r = rg + i*8;
    Wt[(size_t)(n0 + r) * DM_ + k0 + col] = f2bf(t[col][r]);
  }
}

// ---------------------------------------------------------------------------
// Projection GEMM, 128x128 tile, BK=64, both operands bf16 staged with
// global_load_lds (width 16). XOR swizzle folded into per-lane global addr:
// LDS chunk (row, slot) holds global k-chunk  slot ^ (row&7).
// MODE 0 (Q,K): D = Wt * Xb^T -> out[B,H,S,D];  MODE 1 (V): D = Xb * Wt^T -> Vt[B,H,D,S]
// ---------------------------------------------------------------------------
template<int MODE>
__global__ __launch_bounds__(256, 2) void gemm_proj(
    const ushort* __restrict__ Xb, const ushort* __restrict__ Wt,
    const float* __restrict__ bias, ushort* __restrict__ out)
{
  __shared__ __align__(16) ushort lw[128*64];
  __shared__ __align__(16) ushort lx[128*64];
  int tid = threadIdx.x;
  int l = tid & 63, w = tid >> 6;
  int ln = l & 15, lq = l >> 4;
  int sbase = blockIdx.x * 128;
  int fbase = blockIdx.y * 128;
  int wm = w >> 1, wn = w & 1;

  f32x4 acc[4][4];
  #pragma unroll
  for (int i=0;i<4;i++)
    #pragma unroll
    for(int j=0;j<4;j++) acc[i][j] = zero4();

  for (int k0 = 0; k0 < DM_; k0 += 64){
    #pragma unroll
    for (int i = 0; i < 4; i++){
      int inst = w*4 + i;                 // wave-uniform
      int chunk = inst*64 + l;
      int row = chunk >> 3, slot = chunk & 7;
      int kc = slot ^ (row & 7);
      async16((char*)lw + inst*1024,
              &Wt[(size_t)(fbase+row)*DM_ + k0 + kc*8]);
      async16((char*)lx + inst*1024,
              &Xb[(size_t)(sbase+row)*DM_ + k0 + kc*8]);
    }
    __syncthreads();
    const ushort* aS = (MODE==0) ? lw : lx;
    const ushort* bS = (MODE==0) ? lx : lw;
    #pragma unroll
    for (int ks=0; ks<2; ks++){
      bf16x8 af[4], bfr[4];
      #pragma unroll
      for (int i=0;i<4;i++){
        int ar = wm*64 + i*16 + ln;
        int g = ks*4 + lq;
        af[i] = *(const bf16x8*)&aS[ar*64 + (g ^ (ar&7))*8];
      }
      #pragma unroll
      for (int j=0;j<4;j++){
        int br = wn*64 + j*16 + ln;
        int g = ks*4 + lq;
        bfr[j] = *(const bf16x8*)&bS[br*64 + (g ^ (br&7))*8];
      }
      #pragma unroll
      for (int i=0;i<4;i++)
        #pragma unroll
        for (int j=0;j<4;j++)
          acc[i][j] = __builtin_amdgcn_mfma_f32_16x16x32_bf16(af[i], bfr[j], acc[i][j], 0,0,0);
    }
    __syncthreads();
  }

  if (MODE == 0){
    #pragma unroll
    for (int i=0;i<4;i++){
      int fr = fbase + wm*64 + i*16 + (lq<<2);
      float4 bv = *(const float4*)&bias[fr];
      int h = fr >> 6, d0 = fr & 63;
      #pragma unroll
      for (int j=0;j<4;j++){
        int s = sbase + wn*64 + j*16 + ln;
        int b = s >> 11, sq = s & 2047;
        f32x4 v = acc[i][j];
        uint2 pk;
        pk.x = pack2(v.x + bv.x, v.y + bv.y);
        pk.y = pack2(v.z + bv.z, v.w + bv.w);
        *(uint2*)&out[(((size_t)(b*H_ + h))*S_ + sq)*DH_ + d0] = pk;
      }
    }
  } else {
    #pragma unroll
    for (int j=0;j<4;j++){
      int fc = fbase + wn*64 + j*16 + ln;
      float bv = bias[fc];
      int h = fc >> 6, d = fc & 63;
      #pragma unroll
      for (int i=0;i<4;i++){
        int s = sbase + wm*64 + i*16 + (lq<<2);
        int b = s >> 11, sq = s & 2047;
        f32x4 v = acc[i][j];
        uint2 pk;
        pk.x = pack2(v.x + bv, v.y + bv);
        pk.y = pack2(v.z + bv, v.w + bv);
        *(uint2*)&out[(((size_t)(b*H_ + h))*DH_ + d)*S_ + sq] = pk;
      }
    }
  }
}

// ---------------------------------------------------------------------------
// Barrier-free fused attention.
// Block = (head h, 64-q tile), 4 waves; wave w owns q rows [q0+16w, q0+16w+16)
// and computes ALL 4 batches itself: the 4 batch scores land in the same
// lane/reg of 4 per-batch accumulators -> softmax over b is pure in-register.
// Only LDS use: per-wave C-layout -> B-layout transform of P (no barriers).
// ---------------------------------------------------------------------------
__global__ __launch_bounds__(256, 2) void attn(
    const ushort* __restrict__ Q, const ushort* __restrict__ K,
    const ushort* __restrict__ Vt, const float* __restrict__ mask,
    float* __restrict__ out)
{
  __shared__ __align__(16) ushort Pl[4*4*16*32];   // [wave][b][q16][k32] 16 KB
  char* pb = (char*)Pl;
  int tid = threadIdx.x;
  int l = tid & 63, w = tid >> 6;
  int ln = l & 15, lq = l >> 4;

  // XCD swizzle: 16 consecutive per-XCD blocks share q0 (mask L2 reuse)
  int fid = blockIdx.x;
  int xcd = fid & 7, slot = fid >> 3;
  int h = slot & 15;
  int q0 = (xcd*4 + (slot>>4)) * 64;
  int qw = q0 + w*16;                    // this wave's q base

  // persistent Q B-frags: qf[b][ks] = Q[b,h,qw+ln, ks*32+lq*8 ..+8]
  bf16x8 qf[4][2];
  #pragma unroll
  for (int b=0;b<4;b++){
    const ushort* Qbh = Q + ((size_t)(b*H_+h)*S_ + qw)*DH_;
    #pragma unroll
    for (int ks=0;ks<2;ks++)
      qf[b][ks] = *(const bf16x8*)&Qbh[(size_t)ln*DH_ + ks*32 + lq*8];
  }

  f32x4 of[4][4];                        // O^T accum [b][d-tile]
  #pragma unroll
  for (int b=0;b<4;b++)
    #pragma unroll
    for(int j=0;j<4;j++) of[b][j] = zero4();

  const float* mrow = mask + (size_t)(qw + ln)*S_;
  char* pwb = pb + w*4096;               // this wave's LDS region

  for (int kk = 0; kk < S_; kk += 32){
    // mask loads first (longest latency, independent of MFMA)
    float4 mk[4][2];
    #pragma unroll
    for (int b=0;b<4;b++)
      #pragma unroll
      for (int t=0;t<2;t++)
        mk[b][t] = *(const float4*)(mrow + (size_t)b*S_*S_ + kk + t*16 + lq*4);

    // ---- S^T = K * Q^T per batch; C: col=ln->q, row=lq*4+r -> kpos in t-tile
    f32x4 sacc[4][2];
    #pragma unroll
    for (int b=0;b<4;b++){
      const ushort* Kbh = K + (size_t)(b*H_+h)*S_*DH_;
      bf16x8 kf[2][2];
      #pragma unroll
      for (int t=0;t<2;t++)
        #pragma unroll
        for (int ks=0;ks<2;ks++)
          kf[t][ks] = *(const bf16x8*)&Kbh[(size_t)(kk + t*16 + ln)*DH_ + ks*32 + lq*8];
      #pragma unroll
      for (int t=0;t<2;t++){
        f32x4 a = __builtin_amdgcn_mfma_f32_16x16x32_bf16(kf[t][0], qf[b][0], zero4(), 0,0,0);
        sacc[b][t] = __builtin_amdgcn_mfma_f32_16x16x32_bf16(kf[t][1], qf[b][1], a, 0,0,0);
      }
    }

    // ---- softmax over batch, fully in-register ----
    float e[4][2][4];
    #pragma unroll
    for (int t=0;t<2;t++)
      #pragma unroll
      for (int r=0;r<4;r++){
        float s[4];
        #pragma unroll
        for (int b=0;b<4;b++){
          float m = ((const float*)&mk[b][t])[r];
          // exact ref rounding where it matters: fl(m*-1e9); *0.125 is exact
          s[b] = __fadd_rn(sacc[b][t][r]*0.125f, __fmul_rn(m, -1e9f));
        }
        float mx = fmaxf(fmaxf(s[0],s[1]), fmaxf(s[2],s[3]));
        float e0 = __expf(s[0]-mx), e1 = __expf(s[1]-mx);
        float e2 = __expf(s[2]-mx), e3 = __expf(s[3]-mx);
        float inv = __builtin_amdgcn_rcpf((e0+e1)+(e2+e3));
        e[0][t][r]=e0*inv; e[1][t][r]=e1*inv; e[2][t][r]=e2*inv; e[3][t][r]=e3*inv;
      }

    // ---- P -> LDS (per-wave, 16B-chunk XOR swizzle, truncating pack) ----
    // write: lane(ln,lq), t: 8B at row ln, chunk16 (t*2+(lq>>1))^(ln&3), half lq&1
    #pragma unroll
    for (int b=0;b<4;b++){
      #pragma unroll
      for (int t=0;t<2;t++){
        uint2 pk;
        pk.x = packtr(e[b][t][0], e[b][t][1]);
        pk.y = packtr(e[b][t][2], e[b][t][3]);
        *(uint2*)(pwb + b*1024 + ln*64 + ((((t*2)+(lq>>1)) ^ (ln&3))<<4) + ((lq&1)<<3)) = pk;
      }
    }

    // ---- O^T += V^T * P^T per batch (same-wave LDS read, lgkmcnt only) ----
    #pragma unroll
    for (int b=0;b<4;b++){
      const ushort* Vbh = Vt + (size_t)(b*H_+h)*DH_*S_;
      bf16x8 pf = *(const bf16x8*)(pwb + b*1024 + ln*64 + ((lq ^ (ln&3))<<4));
      #pragma unroll
      for (int dt=0;dt<4;dt++){
        bf16x8 vf = *(const bf16x8*)&Vbh[(size_t)(dt*16+ln)*S_ + kk + lq*8];
        of[b][dt] = __builtin_amdgcn_mfma_f32_16x16x32_bf16(vf, pf, of[b][dt], 0,0,0);
      }
    }
  }

  // ---- epilogue: O[b, qw+ln, h*64 + dt*16 + lq*4 + r] ----
  #pragma unroll
  for (int b=0;b<4;b++){
    float* ob = out + ((size_t)b*S_ + qw + ln)*DM_ + h*DH_;
    #pragma unroll
    for (int dt=0;dt<4;dt++)
      *(f32x4*)&ob[dt*16 + lq*4] = of[b][dt];
  }
}

// ---------------------------------------------------------------------------
extern "C" void kernel_launch(void* const* d_in, const int* in_sizes, int n_in,
                              void* d_out, int out_size, void* d_ws, size_t ws_size,
                              hipStream_t stream)
{
  const float* xq   = (const float*)d_in[0];
  const float* xk   = (const float*)d_in[1];
  const float* xv   = (const float*)d_in[2];
  const float* mask = (const float*)d_in[3];
  const float* Wq   = (const float*)d_in[4];
  const float* bq   = (const float*)d_in[5];
  const float* Wk   = (const float*)d_in[6];
  const float* bk   = (const float*)d_in[7];
  const float* Wv   = (const float*)d_in[8];
  const float* bv   = (const float*)d_in[9];
  float* out = (float*)d_out;

  char* ws = (char*)d_ws;                      // 70 MB used
  ushort* Wtq = (ushort*)(ws);                 // 2 MB each
  ushort* Wtk = (ushort*)(ws + (2ull<<20));
  ushort* Wtv = (ushort*)(ws + (4ull<<20));
  ushort* Xbq = (ushort*)(ws + (6ull<<20));    // 16 MB each
  ushort* Xbk = (ushort*)(ws + (22ull<<20));
  ushort* Xbv = (ushort*)(ws + (38ull<<20));
  ushort* Qb  = (ushort*)(ws + (54ull<<20));
  ushort* Kb  = Xbq;                           // reuse: Xbq consumed before Kb written
  ushort* Vtb = Xbk;                           // reuse: Xbk consumed before Vtb written

  conv3<<<dim3(4096,3), 256, 0, stream>>>(xq, xk, xv, Xbq, Xbk, Xbv);
  wtrans3<<<dim3(32,32,3), 256, 0, stream>>>(Wq, Wk, Wv, Wtq, Wtk, Wtv);

  dim3 ggrid(64, 8);
  gemm_proj<0><<<ggrid, 256, 0, stream>>>(Xbq, Wtq, bq, Qb);
  gemm_proj<0><<<ggrid, 256, 0, stream>>>(Xbk, Wtk, bk, Kb);
  gemm_proj<1><<<ggrid, 256, 0, stream>>>(Xbv, Wtv, bv, Vtb);

  attn<<<512, 256, 0, stream>>>(Qb, Kb, Vtb, mask, out);
}

// Round 3
// 574.462 us; speedup vs baseline: 1.6727x; 1.6727x over previous
//
#include <hip/hip_runtime.h>
#include <stdint.h>

#define B_  4
#define S_  2048
#define H_  16
#define DH_ 64
#define DM_ 1024

typedef __attribute__((ext_vector_type(8))) short bf16x8;  // 8 bf16 = 4 VGPR
typedef __attribute__((ext_vector_type(4))) float f32x4;

__device__ __forceinline__ ushort f2bf(float x){
  uint32_t u = __float_as_uint(x);
  u += 0x7FFFu + ((u >> 16) & 1u);   // RNE
  return (ushort)(u >> 16);
}
__device__ __forceinline__ uint32_t pack2(float a, float b){
  return (uint32_t)f2bf(a) | ((uint32_t)f2bf(b) << 16);
}
// truncating bf16 pack (P is in [0,1]; trunc err <= 2^-8 rel): 1 v_perm_b32
__device__ __forceinline__ uint32_t packtr(float a, float b){
  return __builtin_amdgcn_perm(__float_as_uint(b), __float_as_uint(a), 0x07060302u);
}
__device__ __forceinline__ f32x4 zero4(){ f32x4 z; z.x=0.f;z.y=0.f;z.z=0.f;z.w=0.f; return z; }

__device__ __forceinline__ void async16(void* lds, const void* g){
  __builtin_amdgcn_global_load_lds(
      (const __attribute__((address_space(1))) unsigned int*)g,
      (__attribute__((address_space(3))) unsigned int*)lds, 16, 0, 0);
}

// ---------------------------------------------------------------------------
// X fp32 -> bf16 (RNE) for xq, xk (xv is consumed fp32 by gemm_v).
// ---------------------------------------------------------------------------
__global__ __launch_bounds__(256) void conv2(const float* __restrict__ a,
                                             const float* __restrict__ b,
                                             ushort* __restrict__ oa,
                                             ushort* __restrict__ ob){
  const float* src = (blockIdx.y==0) ? a : b;
  ushort* dst      = (blockIdx.y==0) ? oa : ob;
  size_t i = ((size_t)blockIdx.x*256 + threadIdx.x)*8;   // grid covers exactly 8M
  float4 x0 = *(const float4*)&src[i];
  float4 x1 = *(const float4*)&src[i+4];
  uint4 p;
  p.x = pack2(x0.x,x0.y); p.y = pack2(x0.z,x0.w);
  p.z = pack2(x1.x,x1.y); p.w = pack2(x1.z,x1.w);
  *(uint4*)&dst[i] = p;
}

// ---------------------------------------------------------------------------
// W [K][N] fp32 -> Wt [N][K] bf16 (transpose + convert), 3 weights batched.
// ---------------------------------------------------------------------------
__global__ __launch_bounds__(256) void wtrans3(const float* __restrict__ Wq,
                                               const float* __restrict__ Wk,
                                               const float* __restrict__ Wv,
                                               ushort* __restrict__ Tq,
                                               ushort* __restrict__ Tk,
                                               ushort* __restrict__ Tv){
  const float* W = (blockIdx.z==0) ? Wq : (blockIdx.z==1) ? Wk : Wv;
  ushort* Wt     = (blockIdx.z==0) ? Tq : (blockIdx.z==1) ? Tk : Tv;
  __shared__ __align__(16) float t[32][33];
  int n0 = blockIdx.x * 32, k0 = blockIdx.y * 32;
  int col = threadIdx.x & 31, rg = threadIdx.x >> 5;
  #pragma unroll
  for (int i = 0; i < 4; i++){
    int r = rg + i*8;
    t[r][col] = W[(size_t)(k0 + r) * DM_ + n0 + col];
  }
  __syncthreads();
  #pragma unroll
  for (int i = 0; i < 4; i++){
    int r = rg + i*8;
    Wt[(size_t)(n0 + r) * DM_ + k0 + col] = f2bf(t[col][r]);
  }
}

// ---------------------------------------------------------------------------
// Q and K projection GEMMs in ONE dispatch (blockIdx.z selects), 128x128 tile,
// BK=64, both operands staged via global_load_lds w=16, XOR swizzle folded
// into the global address. D = Wt * Xb^T -> out[B,H,S,D].
// ---------------------------------------------------------------------------
__global__ __launch_bounds__(256, 4) void gemm_qk(
    const ushort* __restrict__ Xq, const ushort* __restrict__ Xk,
    const ushort* __restrict__ Wtq, const ushort* __restrict__ Wtk,
    const float* __restrict__ bq, const float* __restrict__ bk,
    ushort* __restrict__ Qo, ushort* __restrict__ Ko)
{
  const ushort* Xb = (blockIdx.z==0) ? Xq : Xk;
  const ushort* Wt = (blockIdx.z==0) ? Wtq : Wtk;
  const float* bias = (blockIdx.z==0) ? bq : bk;
  ushort* out = (blockIdx.z==0) ? Qo : Ko;

  __shared__ __align__(16) ushort lw[128*64];
  __shared__ __align__(16) ushort lx[128*64];
  int tid = threadIdx.x;
  int l = tid & 63, w = tid >> 6;
  int ln = l & 15, lq = l >> 4;
  int sbase = blockIdx.x * 128;
  int fbase = blockIdx.y * 128;
  int wm = w >> 1, wn = w & 1;

  f32x4 acc[4][4];
  #pragma unroll
  for (int i=0;i<4;i++)
    #pragma unroll
    for(int j=0;j<4;j++) acc[i][j] = zero4();

  for (int k0 = 0; k0 < DM_; k0 += 64){
    #pragma unroll
    for (int i = 0; i < 4; i++){
      int inst = w*4 + i;                 // wave-uniform LDS base
      int chunk = inst*64 + l;
      int row = chunk >> 3, slot = chunk & 7;
      int kc = slot ^ (row & 7);
      async16((char*)lw + inst*1024, &Wt[(size_t)(fbase+row)*DM_ + k0 + kc*8]);
      async16((char*)lx + inst*1024, &Xb[(size_t)(sbase+row)*DM_ + k0 + kc*8]);
    }
    __syncthreads();
    #pragma unroll
    for (int ks=0; ks<2; ks++){
      bf16x8 af[4], bfr[4];
      #pragma unroll
      for (int i=0;i<4;i++){
        int ar = wm*64 + i*16 + ln;
        int g = ks*4 + lq;
        af[i] = *(const bf16x8*)&lw[ar*64 + (g ^ (ar&7))*8];
      }
      #pragma unroll
      for (int j=0;j<4;j++){
        int br = wn*64 + j*16 + ln;
        int g = ks*4 + lq;
        bfr[j] = *(const bf16x8*)&lx[br*64 + (g ^ (br&7))*8];
      }
      #pragma unroll
      for (int i=0;i<4;i++)
        #pragma unroll
        for (int j=0;j<4;j++)
          acc[i][j] = __builtin_amdgcn_mfma_f32_16x16x32_bf16(af[i], bfr[j], acc[i][j], 0,0,0);
    }
    __syncthreads();
  }
  // D[m=feature][n=row]; col=ln -> s, row=lq*4+r -> f
  #pragma unroll
  for (int i=0;i<4;i++){
    int fr = fbase + wm*64 + i*16 + (lq<<2);
    float4 bv = *(const float4*)&bias[fr];
    int h = fr >> 6, d0 = fr & 63;
    #pragma unroll
    for (int j=0;j<4;j++){
      int s = sbase + wn*64 + j*16 + ln;
      int b = s >> 11, sq = s & 2047;
      f32x4 v = acc[i][j];
      uint2 pk;
      pk.x = pack2(v.x + bv.x, v.y + bv.y);
      pk.y = pack2(v.z + bv.z, v.w + bv.w);
      *(uint2*)&out[(((size_t)(b*H_ + h))*S_ + sq)*DH_ + d0] = pk;
    }
  }
}

// ---------------------------------------------------------------------------
// V projection: D = X * Wt^T -> Vt[B,H,D,S]. X is fp32 (VALU-converted during
// staging); Wt staged via global_load_lds.
// ---------------------------------------------------------------------------
__global__ __launch_bounds__(256, 2) void gemm_v(
    const float* __restrict__ X, const ushort* __restrict__ Wt,
    const float* __restrict__ bias, ushort* __restrict__ out)
{
  __shared__ __align__(16) ushort lw[128*64];
  __shared__ __align__(16) ushort lx[128*64];
  int tid = threadIdx.x;
  int l = tid & 63, w = tid >> 6;
  int ln = l & 15, lq = l >> 4;
  int sbase = blockIdx.x * 128;
  int fbase = blockIdx.y * 128;
  int wm = w >> 1, wn = w & 1;

  f32x4 acc[4][4];
  #pragma unroll
  for (int i=0;i<4;i++)
    #pragma unroll
    for(int j=0;j<4;j++) acc[i][j] = zero4();

  for (int k0 = 0; k0 < DM_; k0 += 64){
    #pragma unroll
    for (int i = 0; i < 4; i++){
      int inst = w*4 + i;
      int chunk = inst*64 + l;
      int row = chunk >> 3, slot = chunk & 7;
      int kc = slot ^ (row & 7);
      async16((char*)lw + inst*1024, &Wt[(size_t)(fbase+row)*DM_ + k0 + kc*8]);
    }
    #pragma unroll
    for (int r = 0; r < 4; r++){
      int flat = r*256 + tid;
      int row = flat >> 3, c = flat & 7;
      int g = c ^ (row & 7);
      const float* xs = &X[(size_t)(sbase+row)*DM_ + k0 + g*8];
      float4 x0 = *(const float4*)xs;
      float4 x1 = *(const float4*)(xs+4);
      uint4 p;
      p.x = pack2(x0.x, x0.y); p.y = pack2(x0.z, x0.w);
      p.z = pack2(x1.x, x1.y); p.w = pack2(x1.z, x1.w);
      *(uint4*)&lx[row*64 + c*8] = p;
    }
    __syncthreads();
    #pragma unroll
    for (int ks=0; ks<2; ks++){
      bf16x8 af[4], bfr[4];
      #pragma unroll
      for (int i=0;i<4;i++){
        int ar = wm*64 + i*16 + ln;
        int g = ks*4 + lq;
        af[i] = *(const bf16x8*)&lx[ar*64 + (g ^ (ar&7))*8];   // A = X rows
      }
      #pragma unroll
      for (int j=0;j<4;j++){
        int br = wn*64 + j*16 + ln;
        int g = ks*4 + lq;
        bfr[j] = *(const bf16x8*)&lw[br*64 + (g ^ (br&7))*8];  // B = W features
      }
      #pragma unroll
      for (int i=0;i<4;i++)
        #pragma unroll
        for (int j=0;j<4;j++)
          acc[i][j] = __builtin_amdgcn_mfma_f32_16x16x32_bf16(af[i], bfr[j], acc[i][j], 0,0,0);
    }
    __syncthreads();
  }
  // D[m=row][n=feature]; col=ln -> f, row=lq*4+r -> s  => Vt[b,h,d,s]
  #pragma unroll
  for (int j=0;j<4;j++){
    int fc = fbase + wn*64 + j*16 + ln;
    float bv = bias[fc];
    int h = fc >> 6, d = fc & 63;
    #pragma unroll
    for (int i=0;i<4;i++){
      int s = sbase + wm*64 + i*16 + (lq<<2);
      int b = s >> 11, sq = s & 2047;
      f32x4 v = acc[i][j];
      uint2 pk;
      pk.x = pack2(v.x + bv, v.y + bv);
      pk.y = pack2(v.z + bv, v.w + bv);
      *(uint2*)&out[(((size_t)(b*H_ + h))*DH_ + d)*S_ + sq] = pk;
    }
  }
}

// ---------------------------------------------------------------------------
// Fused attention, q-tile = 32, 1024 blocks (4/CU), wave = batch for all
// MFMA/load phases (K/V loads shared via LDS exchange, 64 B/lane/iter).
// Register prefetch: K frags for iter+1, V frags for current iter, and mask
// for iter+1 are issued right after barrier-1 and consumed a softmax+barrier
// later. Softmax over batch is elementwise in k (no online rescale).
// ---------------------------------------------------------------------------
__global__ __launch_bounds__(256, 4) void attn(
    const ushort* __restrict__ Q, const ushort* __restrict__ K,
    const ushort* __restrict__ Vt, const float* __restrict__ mask,
    float* __restrict__ out)
{
  __shared__ __align__(16) float  Sl[B_*32*32];   // 16 KB [b][q32][k32] swizzled
  __shared__ __align__(16) ushort Pl[B_*32*32];   // 8 KB  [b][q32][k32] linear
  int tid = threadIdx.x;
  int l = tid & 63, w = tid >> 6;        // w = batch
  int ln = l & 15, lq = l >> 4;

  // XCD grouping: 16 consecutive same-XCD slots = 16 heads sharing one q-slice
  int fid = blockIdx.x;
  int xcd = fid & 7, slot = fid >> 3;    // 128 slots per XCD
  int h = slot & 15;
  int qt = (slot >> 4) * 8 + xcd;        // 0..63
  int q0 = qt * 32;

  const ushort* Qbh = Q  + (((size_t)(w*H_ + h))*S_ + q0)*DH_;
  const ushort* Kbh = K  + ((size_t)(w*H_ + h))*S_*DH_;
  const ushort* Vbh = Vt + ((size_t)(w*H_ + h))*DH_*S_;

  // persistent Q B-frags
  bf16x8 qf[2][2];
  #pragma unroll
  for (int q2=0;q2<2;q2++)
    #pragma unroll
    for (int ks=0;ks<2;ks++)
      qf[q2][ks] = *(const bf16x8*)&Qbh[(size_t)(q2*16 + ln)*DH_ + ks*32 + lq*8];

  f32x4 of[4][2];                        // O^T accum [d-tile][q-subtile]
  #pragma unroll
  for (int i=0;i<4;i++)
    #pragma unroll
    for(int j=0;j<2;j++) of[i][j] = zero4();

  // softmax-phase identity: lane -> (q row, 4-k chunk)
  int q_sm = w*8 + (l >> 3);             // 0..31
  int kc2  = l & 7;                      // chunk of 4 k
  const float* mrow = mask + (size_t)(q0 + q_sm)*S_ + kc2*4;

  // prologue: prefetch K frags and mask for kk=0
  bf16x8 kf[2][2];
  float4 mk[4];
  #pragma unroll
  for (int t=0;t<2;t++)
    #pragma unroll
    for (int ks=0;ks<2;ks++)
      kf[t][ks] = *(const bf16x8*)&Kbh[(size_t)(t*16 + ln)*DH_ + ks*32 + lq*8];
  #pragma unroll
  for (int b2=0;b2<4;b2++)
    mk[b2] = *(const float4*)(mrow + (size_t)b2*S_*S_);

  for (int kk = 0; kk < S_; kk += 32){
    int kn = (kk + 32) & (S_ - 1);       // wrapped prefetch row (last iter harmless)

    // ---- S^T = K * Q^T (kf already in regs) ----
    f32x4 sacc[2][2];
    #pragma unroll
    for (int t=0;t<2;t++)
      #pragma unroll
      for (int q2=0;q2<2;q2++){
        f32x4 a = __builtin_amdgcn_mfma_f32_16x16x32_bf16(kf[t][0], qf[q2][0], zero4(), 0,0,0);
        sacc[t][q2] = __builtin_amdgcn_mfma_f32_16x16x32_bf16(kf[t][1], qf[q2][1], a, 0,0,0);
      }
    // store S^T: row q (32 floats), chunk (t*4+lq)^(q&7)  -> conflict-free
    #pragma unroll
    for (int t=0;t<2;t++)
      #pragma unroll
      for (int q2=0;q2<2;q2++){
        int q = q2*16 + ln;
        *(f32x4*)&Sl[w*1024 + q*32 + ((t*4 + lq) ^ (q & 7))*4] = sacc[t][q2];
      }
    __syncthreads();

    // ---- prefetch: K frags (kk+32), V frags (kk) ----
    #pragma unroll
    for (int t=0;t<2;t++)
      #pragma unroll
      for (int ks=0;ks<2;ks++)
        kf[t][ks] = *(const bf16x8*)&Kbh[(size_t)(kn + t*16 + ln)*DH_ + ks*32 + lq*8];
    bf16x8 vf[4];
    #pragma unroll
    for (int dt=0;dt<4;dt++)
      vf[dt] = *(const bf16x8*)&Vbh[(size_t)(dt*16 + ln)*S_ + kk + lq*8];

    // ---- softmax over batch (mask mk[] preloaded last iter) ----
    f32x4 sr[4];
    #pragma unroll
    for (int b2=0;b2<4;b2++)
      sr[b2] = *(const f32x4*)&Sl[b2*1024 + q_sm*32 + ((kc2) ^ (q_sm & 7))*4];
    float p[4][4];
    #pragma unroll
    for (int j=0;j<4;j++){
      float s0 = __builtin_fmaf(sr[0][j], 0.125f, __fmul_rn(((const float*)&mk[0])[j], -1e9f));
      float s1 = __builtin_fmaf(sr[1][j], 0.125f, __fmul_rn(((const float*)&mk[1])[j], -1e9f));
      float s2 = __builtin_fmaf(sr[2][j], 0.125f, __fmul_rn(((const float*)&mk[2])[j], -1e9f));
      float s3 = __builtin_fmaf(sr[3][j], 0.125f, __fmul_rn(((const float*)&mk[3])[j], -1e9f));
      float mx = fmaxf(fmaxf(s0,s1), fmaxf(s2,s3));
      float e0 = __expf(s0-mx), e1 = __expf(s1-mx);
      float e2 = __expf(s2-mx), e3 = __expf(s3-mx);
      float inv = __builtin_amdgcn_rcpf((e0+e1)+(e2+e3));
      p[0][j]=e0*inv; p[1][j]=e1*inv; p[2][j]=e2*inv; p[3][j]=e3*inv;
    }
    // prefetch mask for next iter (consumed next softmax phase)
    #pragma unroll
    for (int b2=0;b2<4;b2++)
      mk[b2] = *(const float4*)(mrow + (size_t)b2*S_*S_ + kn);
    // write P (linear layout is conflict-free for both sides)
    #pragma unroll
    for (int b2=0;b2<4;b2++){
      uint2 pk;
      pk.x = packtr(p[b2][0], p[b2][1]);
      pk.y = packtr(p[b2][2], p[b2][3]);
      *(uint2*)((char*)Pl + b2*2048 + q_sm*64 + kc2*8) = pk;
    }
    __syncthreads();

    // ---- O^T += V^T * P^T (vf prefetched above) ----
    bf16x8 pf[2];
    #pragma unroll
    for (int q2=0;q2<2;q2++)
      pf[q2] = *(const bf16x8*)((char*)Pl + w*2048 + (q2*16 + ln)*64 + lq*16);
    #pragma unroll
    for (int dt=0;dt<4;dt++)
      #pragma unroll
      for (int q2=0;q2<2;q2++)
        of[dt][q2] = __builtin_amdgcn_mfma_f32_16x16x32_bf16(vf[dt], pf[q2], of[dt][q2], 0,0,0);
  }

  // ---- epilogue: O[b, q0+q, h*64 + d], 4 consecutive d per lane ----
  #pragma unroll
  for (int q2=0;q2<2;q2++){
    float* ob = out + ((size_t)w*S_ + q0 + q2*16 + ln)*DM_ + h*DH_;
    #pragma unroll
    for (int dt=0;dt<4;dt++)
      *(f32x4*)&ob[dt*16 + lq*4] = of[dt][q2];
  }
}

// ---------------------------------------------------------------------------
extern "C" void kernel_launch(void* const* d_in, const int* in_sizes, int n_in,
                              void* d_out, int out_size, void* d_ws, size_t ws_size,
                              hipStream_t stream)
{
  const float* xq   = (const float*)d_in[0];
  const float* xk   = (const float*)d_in[1];
  const float* xv   = (const float*)d_in[2];
  const float* mask = (const float*)d_in[3];
  const float* Wq   = (const float*)d_in[4];
  const float* bq   = (const float*)d_in[5];
  const float* Wk   = (const float*)d_in[6];
  const float* bk   = (const float*)d_in[7];
  const float* Wv   = (const float*)d_in[8];
  const float* bv   = (const float*)d_in[9];
  float* out = (float*)d_out;

  char* ws = (char*)d_ws;                      // 70 MB used
  ushort* Wtq = (ushort*)(ws);                 // 2 MB each
  ushort* Wtk = (ushort*)(ws + (2ull<<20));
  ushort* Wtv = (ushort*)(ws + (4ull<<20));
  ushort* Xbq = (ushort*)(ws + (6ull<<20));    // 16 MB each
  ushort* Xbk = (ushort*)(ws + (22ull<<20));
  ushort* Qb  = (ushort*)(ws + (38ull<<20));
  ushort* Kb  = (ushort*)(ws + (54ull<<20));
  ushort* Vtb = Xbq;                           // safe: Xbq consumed by gemm_qk before gemm_v runs

  conv2<<<dim3(4096,2), 256, 0, stream>>>(xq, xk, Xbq, Xbk);
  wtrans3<<<dim3(32,32,3), 256, 0, stream>>>(Wq, Wk, Wv, Wtq, Wtk, Wtv);

  gemm_qk<<<dim3(64,8,2), 256, 0, stream>>>(Xbq, Xbk, Wtq, Wtk, bq, bk, Qb, Kb);
  gemm_v<<<dim3(64,8), 256, 0, stream>>>(xv, Wtv, bv, Vtb);

  attn<<<1024, 256, 0, stream>>>(Qb, Kb, Vtb, mask, out);
}